// Round 10
// baseline (158.621 us; speedup 1.0000x reference)
//
#include <hip/hip_runtime.h>

typedef _Float16 half_t;
typedef _Float16 half2_t __attribute__((ext_vector_type(2)));
typedef _Float16 half4_t __attribute__((ext_vector_type(4)));
typedef _Float16 half8 __attribute__((ext_vector_type(8)));
typedef float f32x4 __attribute__((ext_vector_type(4)));
typedef float f32x16 __attribute__((ext_vector_type(16)));
typedef unsigned uint4v __attribute__((ext_vector_type(4)));

__device__ __forceinline__ void gload_lds16(const void* g, void* l) {
    __builtin_amdgcn_global_load_lds(
        (const __attribute__((address_space(1))) void*)g,
        (__attribute__((address_space(3))) void*)l, 16, 0, 0);
}

// ---------------- cast fp32 -> fp16 (x) ----------------
__global__ __launch_bounds__(256) void cast_f32_f16(const float* __restrict__ s,
                                                    half_t* __restrict__ d, int n) {
    const int stride = gridDim.x * blockDim.x;
    for (int i = blockIdx.x * blockDim.x + threadIdx.x; i * 4 < n; i += stride) {
        const float4 v = *(const float4*)(s + (long)i * 4);
        half4_t h = {(half_t)v.x, (half_t)v.y, (half_t)v.z, (half_t)v.w};
        *(half4_t*)(d + (long)i * 4) = h;
    }
}

// ---------------- cast 4 weight matrices into one contiguous fp16 region ----------------
__global__ __launch_bounds__(256) void cast_w4(const float* __restrict__ w0,
                                               const float* __restrict__ w1,
                                               const float* __restrict__ w2,
                                               const float* __restrict__ w3,
                                               half_t* __restrict__ d) {
    const int i = blockIdx.x * blockDim.x + threadIdx.x;   // float4 index
    const int which = i / 147456;                          // 768*768/4
    const int off = i - which * 147456;
    const float* s = which == 0 ? w0 : which == 1 ? w1 : which == 2 ? w2 : w3;
    const float4 v = *(const float4*)(s + (long)off * 4);
    half4_t h = {(half_t)v.x, (half_t)v.y, (half_t)v.z, (half_t)v.w};
    *(half4_t*)(d + (long)i * 4) = h;
}

__global__ __launch_bounds__(256) void concat_bias(const float* __restrict__ a,
                                                   const float* __restrict__ b,
                                                   const float* __restrict__ c,
                                                   float* __restrict__ o) {
    int i = blockIdx.x * blockDim.x + threadIdx.x;
    if (i < 768) o[i] = a[i];
    else if (i < 1536) o[i] = b[i - 768];
    else if (i < 2304) o[i] = c[i - 1536];
}

// ---------------- GEMM: 128x128 tile, BK=32, TRIPLE-buffered, 3 blocks/CU ----------------
// C[8192,N] = A[8192,768] * W[N,768]^T + bias.  K = 768 (NT = 24 steps of 32).
// LDS layout is K-major chunk-planes: L[buf][mat][plane=k/8][row][8 halfs].
//  - staging: linear global_load_lds (lane l -> row l), no swizzle needed
//  - fragment reads: 16 consecutive rows x 16B at fixed plane -> conflict-free
// 48 KiB LDS -> 3 blocks/CU resident; 3-deep prefetch with s_waitcnt vmcnt(8)
// (4 loads per stage per wave) gives each stage 2 K-steps of latency budget.
// VSPLIT: N-tiles >=12 (cols 1536..2303 = V) are written TRANSPOSED into Vt.
template <typename OutT, bool VSPLIT>
__global__ __launch_bounds__(256) void gemm3(const half_t* __restrict__ A,
                                             const half_t* __restrict__ W,
                                             const float* __restrict__ bias,
                                             OutT* __restrict__ C,
                                             half_t* __restrict__ Vt,
                                             const int N) {
    constexpr int Kdim = 768, NT = 24;
    alignas(16) __shared__ half_t L[3][2][4][128][8];   // 48 KiB

    const int t = threadIdx.x, l = t & 63, wv = t >> 6;
    const int wr = wv >> 1, wc = wv & 1;                 // 2M x 2N waves
    const int m0 = blockIdx.x * 128, n0 = blockIdx.y * 128;

    f32x4 acc[4][4] = {};

    const half_t* Ag = A + (long)m0 * Kdim;
    const half_t* Wg = W + (long)n0 * Kdim;

    // staging: wave wv, round rd -> plane p = rd*2 + (wv>>1), rows (wv&1)*64 + l
    const int sp_hi = wv >> 1;                           // plane offset bit
    const int srow = (wv & 1) * 64;                      // row-block base

    auto STAGE = [&](int tile, int buf) {
        const int k0 = tile * 32;
#pragma unroll
        for (int rd = 0; rd < 2; ++rd) {
            const int p = rd * 2 + sp_hi;
            gload_lds16(Ag + (long)(srow + l) * Kdim + k0 + p * 8,
                        &L[buf][0][p][srow][0]);
            gload_lds16(Wg + (long)(srow + l) * Kdim + k0 + p * 8,
                        &L[buf][1][p][srow][0]);
        }
    };

    auto COMPUTE = [&](int buf) {
        const int kc = l >> 4;                           // plane 0..3
        half8 afr[4], bfr[4];
#pragma unroll
        for (int i = 0; i < 4; ++i) {
            const int arow = wr * 64 + i * 16 + (l & 15);
            afr[i] = *(const half8*)&L[buf][0][kc][arow][0];
            const int brow = wc * 64 + i * 16 + (l & 15);
            bfr[i] = *(const half8*)&L[buf][1][kc][brow][0];
        }
#pragma unroll
        for (int mi = 0; mi < 4; ++mi)
#pragma unroll
            for (int ni = 0; ni < 4; ++ni)
                acc[mi][ni] = __builtin_amdgcn_mfma_f32_16x16x32_f16(
                    afr[mi], bfr[ni], acc[mi][ni], 0, 0, 0);
    };

    STAGE(0, 0);
    STAGE(1, 1);
    STAGE(2, 2);

    int cur = 0;
    for (int tt = 0; tt < NT - 2; ++tt) {
        asm volatile("s_waitcnt vmcnt(8)" ::: "memory");
        __builtin_amdgcn_s_barrier();
        asm volatile("" ::: "memory");
        COMPUTE(cur);
        asm volatile("" ::: "memory");
        __builtin_amdgcn_s_barrier();
        if (tt + 3 < NT) STAGE(tt + 3, cur);
        cur = cur == 2 ? 0 : cur + 1;
    }
    // tt = NT-2
    asm volatile("s_waitcnt vmcnt(4)" ::: "memory");
    __builtin_amdgcn_s_barrier();
    asm volatile("" ::: "memory");
    COMPUTE(cur);
    asm volatile("" ::: "memory");
    __builtin_amdgcn_s_barrier();
    cur = cur == 2 ? 0 : cur + 1;
    // tt = NT-1
    asm volatile("s_waitcnt vmcnt(0)" ::: "memory");
    __builtin_amdgcn_s_barrier();
    asm volatile("" ::: "memory");
    COMPUTE(cur);

    // ---- epilogue ----
    const bool vtile = VSPLIT && (blockIdx.y >= 12);     // pure-V N-tiles
#pragma unroll
    for (int ni = 0; ni < 4; ++ni) {
        const int col = n0 + wc * 64 + ni * 16 + (l & 15);
        const float bb = bias[col];
        if (!vtile) {
#pragma unroll
            for (int mi = 0; mi < 4; ++mi) {
                const int row = m0 + wr * 64 + mi * 16 + (l >> 4) * 4;
#pragma unroll
                for (int r = 0; r < 4; ++r)
                    C[(long)(row + r) * N + col] = (OutT)(acc[mi][ni][r] + bb);
            }
        } else {
            const int hd = col - 1536;
            const int hidx = hd >> 6, d = hd & 63;
#pragma unroll
            for (int mi = 0; mi < 4; ++mi) {
                const int row = m0 + wr * 64 + mi * 16 + (l >> 4) * 4;
                const int b = row >> 10, n = row & 1023;
                half4_t pk;
#pragma unroll
                for (int r = 0; r < 4; ++r) pk[r] = (half_t)(acc[mi][ni][r] + bb);
                *(half4_t*)(Vt + ((long)((b * 12 + hidx) * 64 + d)) * 1024 + n) = pk;
            }
        }
    }
}

// ---------------- flash attention v5 (unchanged) ----------------
__global__ __launch_bounds__(256) void attn5_kernel(const half_t* __restrict__ qkv,
                                                    const half_t* __restrict__ Vt,
                                                    const float* __restrict__ head_mask,
                                                    half_t* __restrict__ Y) {
    alignas(16) __shared__ half_t Kl[2][64 * 64];
    alignas(16) __shared__ half_t Vl[2][64 * 64];

    const int t = threadIdx.x, l = t & 63, wv = t >> 6;
    const int h2 = l >> 5, q32 = l & 31;
    const int bh = blockIdx.x, b = bh / 12, hh = bh % 12;
    const int q0 = blockIdx.y * 128 + wv * 32;

    half8 qf[4];
    {
        const half_t SC = (half_t)(0.125f * 1.44269504f);
        const half_t* Qp = qkv + ((long)(b * 1024 + q0 + q32)) * 2304 + hh * 64 + h2 * 8;
#pragma unroll
        for (int kd = 0; kd < 4; ++kd) {
            half8 v = *(const half8*)(Qp + kd * 16);
#pragma unroll
            for (int j = 0; j < 8; ++j) v[j] = v[j] * SC;
            qf[kd] = v;
        }
    }

    const half8 ONES = {(half_t)1, (half_t)1, (half_t)1, (half_t)1,
                        (half_t)1, (half_t)1, (half_t)1, (half_t)1};

    const half_t* Kg = qkv + (long)b * 1024 * 2304 + 768 + hh * 64;
    const half_t* Vg = Vt + (long)bh * 64 * 1024;

    const int srow_lo = (l >> 3);
    const int schunk = l & 7;

    auto STAGE = [&](int tile, int bf) {
#pragma unroll
        for (int c = 0; c < 2; ++c) {
            const int row = c * 32 + wv * 8 + srow_lo;
            const int sc_ = (schunk ^ (row & 7)) * 8;
            gload_lds16(Kg + (long)(tile * 64 + row) * 2304 + sc_,
                        &Kl[bf][(c * 32 + wv * 8) * 64]);
            gload_lds16(Vg + (long)row * 1024 + tile * 64 + sc_,
                        &Vl[bf][(c * 32 + wv * 8) * 64]);
        }
    };

    f32x16 o0 = {}, o1 = {}, lacc = {};

    STAGE(0, 0);

    for (int tt = 0; tt < 16; ++tt) {
        const int bf = tt & 1;
        if (tt < 15) {
            STAGE(tt + 1, bf ^ 1);
            asm volatile("s_waitcnt vmcnt(4)" ::: "memory");
        } else {
            asm volatile("s_waitcnt vmcnt(0)" ::: "memory");
        }
        __builtin_amdgcn_s_barrier();
        asm volatile("" ::: "memory");

        f32x16 s0 = {}, s1 = {};
        __builtin_amdgcn_s_setprio(1);
#pragma unroll
        for (int kd = 0; kd < 4; ++kd) {
            const int ch = ((kd * 2 + h2) ^ (q32 & 7)) * 8;
            half8 k0 = *(const half8*)&Kl[bf][q32 * 64 + ch];
            half8 k1 = *(const half8*)&Kl[bf][(32 + q32) * 64 + ch];
            s0 = __builtin_amdgcn_mfma_f32_32x32x16_f16(k0, qf[kd], s0, 0, 0, 0);
            s1 = __builtin_amdgcn_mfma_f32_32x32x16_f16(k1, qf[kd], s1, 0, 0, 0);
        }
        __builtin_amdgcn_s_setprio(0);

#pragma unroll
        for (int kc = 0; kc < 4; ++kc) {
            const f32x16& ss = (kc >> 1) ? s1 : s0;
            const int rb = (kc & 1) * 8;
            unsigned pw[4];
#pragma unroll
            for (int k2 = 0; k2 < 4; ++k2) {
                const float a = __builtin_amdgcn_exp2f(ss[rb + 2 * k2]);
                const float c = __builtin_amdgcn_exp2f(ss[rb + 2 * k2 + 1]);
                pw[k2] = __builtin_bit_cast(unsigned, __builtin_amdgcn_cvt_pkrtz(a, c));
            }
            uint4v uu = {pw[0], pw[1], pw[2], pw[3]};
            const half8 pf = __builtin_bit_cast(half8, uu);

            const int g0 = 2 * kc;
            const int a0 = q32 * 64 + ((g0 ^ (q32 & 7)) * 8) + 4 * h2;
            const int a1 = q32 * 64 + (((g0 + 1) ^ (q32 & 7)) * 8) + 4 * h2;
            const int r2 = 32 + q32;
            const int b0 = r2 * 64 + ((g0 ^ (r2 & 7)) * 8) + 4 * h2;
            const int b1 = r2 * 64 + (((g0 + 1) ^ (r2 & 7)) * 8) + 4 * h2;
            half4_t va0 = *(const half4_t*)&Vl[bf][a0];
            half4_t va1 = *(const half4_t*)&Vl[bf][a1];
            half4_t vb0 = *(const half4_t*)&Vl[bf][b0];
            half4_t vb1 = *(const half4_t*)&Vl[bf][b1];
            half8 vf0 = {va0[0], va0[1], va0[2], va0[3], va1[0], va1[1], va1[2], va1[3]};
            half8 vf1 = {vb0[0], vb0[1], vb0[2], vb0[3], vb1[0], vb1[1], vb1[2], vb1[3]};

            __builtin_amdgcn_s_setprio(1);
            o0 = __builtin_amdgcn_mfma_f32_32x32x16_f16(vf0, pf, o0, 0, 0, 0);
            o1 = __builtin_amdgcn_mfma_f32_32x32x16_f16(vf1, pf, o1, 0, 0, 0);
            lacc = __builtin_amdgcn_mfma_f32_32x32x16_f16(ONES, pf, lacc, 0, 0, 0);
            __builtin_amdgcn_s_setprio(0);
        }

        asm volatile("" ::: "memory");
        __builtin_amdgcn_s_barrier();
    }

    const float hmv = head_mask[b * 12 + hh];
    const float sc = hmv * hmv / lacc[0];
    half_t* Yp = Y + ((long)(b * 1024 + q0 + q32)) * 768 + hh * 64;
#pragma unroll
    for (int db = 0; db < 2; ++db) {
        const f32x16 oo = db ? o1 : o0;
#pragma unroll
        for (int rq = 0; rq < 4; ++rq) {
            half4_t pk;
#pragma unroll
            for (int i = 0; i < 4; ++i) pk[i] = (half_t)(oo[rq * 4 + i] * sc);
            *(half4_t*)(Yp + db * 32 + rq * 8 + h2 * 4) = pk;
        }
    }
}

// ---------------- launch ----------------
extern "C" void kernel_launch(void* const* d_in, const int* in_sizes, int n_in,
                              void* d_out, int out_size, void* d_ws, size_t ws_size,
                              hipStream_t stream) {
    const float* x   = (const float*)d_in[0];
    const float* hm  = (const float*)d_in[1];
    const float* q_w = (const float*)d_in[2];
    const float* q_b = (const float*)d_in[3];
    const float* k_w = (const float*)d_in[4];
    const float* k_b = (const float*)d_in[5];
    const float* v_w = (const float*)d_in[6];
    const float* v_b = (const float*)d_in[7];
    const float* p_w = (const float*)d_in[8];
    const float* p_b = (const float*)d_in[9];
    float* out = (float*)d_out;

    char* ws = (char*)d_ws;
    half_t* xh  = (half_t*)(ws);                    // 8192*768*2   = 12582912
    half_t* wc  = (half_t*)(ws + 12582912);         // [qkv|proj] weights fp16
    half_t* pwh = (half_t*)(ws + 16121856);         //   (proj part of wc)
    float*  bc  = (float*)(ws + 17301504);          // 2304*4
    half_t* qkv = (half_t*)(ws + 17310720);         // 8192*2304*2  = 37748736
    half_t* y   = (half_t*)(ws + 55059456);         // 8192*768*2   = 12582912
    half_t* Vt = (ws_size >= (size_t)67642368 + 12582912)
                     ? (half_t*)(ws + 67642368)
                     : (half_t*)d_out;

    cast_f32_f16<<<2048, 256, 0, stream>>>(x, xh, 8192 * 768);
    cast_w4<<<2304, 256, 0, stream>>>(q_w, k_w, v_w, p_w, wc);
    concat_bias<<<9, 256, 0, stream>>>(q_b, k_b, v_b, bc);

    gemm3<half_t, true><<<dim3(64, 18), 256, 0, stream>>>(xh, wc, bc, qkv, Vt, 2304);
    attn5_kernel<<<dim3(96, 8), 256, 0, stream>>>(qkv, Vt, hm, y);
    gemm3<float, false><<<dim3(64, 6), 256, 0, stream>>>(y, pwh, p_b, out, nullptr, 768);
}

// Round 11
// 121.821 us; speedup vs baseline: 1.3021x; 1.3021x over previous
//
#include <hip/hip_runtime.h>

typedef _Float16 half_t;
typedef _Float16 half2_t __attribute__((ext_vector_type(2)));
typedef _Float16 half4_t __attribute__((ext_vector_type(4)));
typedef _Float16 half8 __attribute__((ext_vector_type(8)));
typedef float f32x4 __attribute__((ext_vector_type(4)));
typedef float f32x16 __attribute__((ext_vector_type(16)));
typedef unsigned uint4v __attribute__((ext_vector_type(4)));

__device__ __forceinline__ void gload_lds16(const void* g, void* l) {
    __builtin_amdgcn_global_load_lds(
        (const __attribute__((address_space(1))) void*)g,
        (__attribute__((address_space(3))) void*)l, 16, 0, 0);
}

// ---------------- cast fp32 -> fp16 (x) ----------------
__global__ __launch_bounds__(256) void cast_f32_f16(const float* __restrict__ s,
                                                    half_t* __restrict__ d, int n) {
    const int stride = gridDim.x * blockDim.x;
    for (int i = blockIdx.x * blockDim.x + threadIdx.x; i * 4 < n; i += stride) {
        const float4 v = *(const float4*)(s + (long)i * 4);
        half4_t h = {(half_t)v.x, (half_t)v.y, (half_t)v.z, (half_t)v.w};
        *(half4_t*)(d + (long)i * 4) = h;
    }
}

// ---------------- cast 4 weight matrices into one contiguous fp16 region ----------------
__global__ __launch_bounds__(256) void cast_w4(const float* __restrict__ w0,
                                               const float* __restrict__ w1,
                                               const float* __restrict__ w2,
                                               const float* __restrict__ w3,
                                               half_t* __restrict__ d) {
    const int i = blockIdx.x * blockDim.x + threadIdx.x;   // float4 index
    const int which = i / 147456;                          // 768*768/4
    const int off = i - which * 147456;
    const float* s = which == 0 ? w0 : which == 1 ? w1 : which == 2 ? w2 : w3;
    const float4 v = *(const float4*)(s + (long)off * 4);
    half4_t h = {(half_t)v.x, (half_t)v.y, (half_t)v.z, (half_t)v.w};
    *(half4_t*)(d + (long)i * 4) = h;
}

__global__ __launch_bounds__(256) void concat_bias(const float* __restrict__ a,
                                                   const float* __restrict__ b,
                                                   const float* __restrict__ c,
                                                   float* __restrict__ o) {
    int i = blockIdx.x * blockDim.x + threadIdx.x;
    if (i < 768) o[i] = a[i];
    else if (i < 1536) o[i] = b[i - 768];
    else if (i < 2304) o[i] = c[i - 1536];
}

// ---------------- GEMM: 256x128 tile, BK=32, 3-buffer phase pipeline ----------------
// C[8192,N] = A[8192,768] * W[N,768]^T + bias.  K=768 -> NT=24 K-tiles of 32.
// 8 waves (2M x 4N), per-wave C = 128x32 = 8x2 fragments -> 16 MFMA/phase.
// 3 LDS buffers (72 KiB) -> 2 blocks/CU.  Phase p: vmcnt(3) retires tile p's
// stage loads (ledger: outstanding = tiles p+1,p+2 = 6 loads); barrier;
// ds_read frags of tile p; issue STAGE(tile p+2); 16 MFMA.  Prefetch lag =
// 2 phases.  LDS chunk-XOR swizzle (c ^ ((row>>1)&3)) on both stage-source
// and ds_read -> max 2-way bank aliasing (free).
// VSPLIT: N-tiles >=12 (cols 1536..2303 = V) are written TRANSPOSED into Vt.
template <typename OutT, bool VSPLIT>
__global__ __launch_bounds__(512, 4) void gemm8p(const half_t* __restrict__ A,
                                                 const half_t* __restrict__ W,
                                                 const float* __restrict__ bias,
                                                 OutT* __restrict__ C,
                                                 half_t* __restrict__ Vt,
                                                 const int N) {
    constexpr int Kdim = 768, NT = 24;
    alignas(16) __shared__ half_t Ab[3][256][32];   // 48 KiB
    alignas(16) __shared__ half_t Bb[3][128][32];   // 24 KiB

    const int t = threadIdx.x, l = t & 63, wv = t >> 6;
    const int wr = wv >> 2, wc = wv & 3;             // 2M x 4N waves
    const int m0 = blockIdx.x * 256, n0 = blockIdx.y * 128;

    f32x4 acc[8][2] = {};

    const half_t* Ag = A + (long)m0 * Kdim;
    const half_t* Wg = W + (long)n0 * Kdim;

    // stage coords: lane l -> row base+(l>>2), chunk' = l&3; source k-chunk
    // c = chunk' ^ ((row>>1)&3) (self-inverse) so ds_read with the same XOR
    // sees linear k.  Dest is wave-uniform 1KB region (gload_lds rule).
    auto STAGE = [&](int tile) {
        const int buf = tile % 3;
        const int k0 = tile * 32;
#pragma unroll
        for (int r = 0; r < 2; ++r) {                // A: 2 rounds x 16 rows
            const int row = (wv * 2 + r) * 16 + (l >> 2);
            const int c = (l & 3) ^ ((row >> 1) & 3);
            gload_lds16(Ag + (long)row * Kdim + k0 + c * 8,
                        &Ab[buf][(wv * 2 + r) * 16][0]);
        }
        {                                            // B: 1 round x 16 rows
            const int row = wv * 16 + (l >> 2);
            const int c = (l & 3) ^ ((row >> 1) & 3);
            gload_lds16(Wg + (long)row * Kdim + k0 + c * 8,
                        &Bb[buf][wv * 16][0]);
        }
    };

    STAGE(0);
    STAGE(1);

    for (int p = 0; p < NT; ++p) {
        const int buf = p % 3;
        if (p < NT - 1) {
            asm volatile("s_waitcnt vmcnt(3)" ::: "memory");
        } else {
            asm volatile("s_waitcnt vmcnt(0)" ::: "memory");
        }
        __builtin_amdgcn_s_barrier();
        asm volatile("" ::: "memory");

        half8 afr[8], bfr[2];
#pragma unroll
        for (int ni = 0; ni < 2; ++ni) {
            const int brow = wc * 32 + ni * 16 + (l & 15);
            const int c = (l >> 4) ^ ((brow >> 1) & 3);
            bfr[ni] = *(const half8*)&Bb[buf][brow][c * 8];
        }
#pragma unroll
        for (int mi = 0; mi < 8; ++mi) {
            const int arow = wr * 128 + mi * 16 + (l & 15);
            const int c = (l >> 4) ^ ((arow >> 1) & 3);
            afr[mi] = *(const half8*)&Ab[buf][arow][c * 8];
        }

        if (p + 2 < NT) STAGE(p + 2);

        __builtin_amdgcn_s_setprio(1);
#pragma unroll
        for (int mi = 0; mi < 8; ++mi)
#pragma unroll
            for (int ni = 0; ni < 2; ++ni)
                acc[mi][ni] = __builtin_amdgcn_mfma_f32_16x16x32_f16(
                    afr[mi], bfr[ni], acc[mi][ni], 0, 0, 0);
        __builtin_amdgcn_s_setprio(0);
    }

    // ---- epilogue ----
    const bool vtile = VSPLIT && (blockIdx.y >= 12);     // pure-V N-tiles
#pragma unroll
    for (int ni = 0; ni < 2; ++ni) {
        const int col = n0 + wc * 32 + ni * 16 + (l & 15);
        const float bb = bias[col];
        if (!vtile) {
#pragma unroll
            for (int mi = 0; mi < 8; ++mi) {
                const int row = m0 + wr * 128 + mi * 16 + (l >> 4) * 4;
#pragma unroll
                for (int r = 0; r < 4; ++r)
                    C[(long)(row + r) * N + col] = (OutT)(acc[mi][ni][r] + bb);
            }
        } else {
            const int hd = col - 1536;
            const int hidx = hd >> 6, d = hd & 63;
#pragma unroll
            for (int mi = 0; mi < 8; ++mi) {
                const int row = m0 + wr * 128 + mi * 16 + (l >> 4) * 4;
                const int b = row >> 10, n = row & 1023;
                half4_t pk;
#pragma unroll
                for (int r = 0; r < 4; ++r) pk[r] = (half_t)(acc[mi][ni][r] + bb);
                *(half4_t*)(Vt + ((long)((b * 12 + hidx) * 64 + d)) * 1024 + n) = pk;
            }
        }
    }
}

// ---------------- flash attention v5 (unchanged) ----------------
__global__ __launch_bounds__(256) void attn5_kernel(const half_t* __restrict__ qkv,
                                                    const half_t* __restrict__ Vt,
                                                    const float* __restrict__ head_mask,
                                                    half_t* __restrict__ Y) {
    alignas(16) __shared__ half_t Kl[2][64 * 64];
    alignas(16) __shared__ half_t Vl[2][64 * 64];

    const int t = threadIdx.x, l = t & 63, wv = t >> 6;
    const int h2 = l >> 5, q32 = l & 31;
    const int bh = blockIdx.x, b = bh / 12, hh = bh % 12;
    const int q0 = blockIdx.y * 128 + wv * 32;

    half8 qf[4];
    {
        const half_t SC = (half_t)(0.125f * 1.44269504f);
        const half_t* Qp = qkv + ((long)(b * 1024 + q0 + q32)) * 2304 + hh * 64 + h2 * 8;
#pragma unroll
        for (int kd = 0; kd < 4; ++kd) {
            half8 v = *(const half8*)(Qp + kd * 16);
#pragma unroll
            for (int j = 0; j < 8; ++j) v[j] = v[j] * SC;
            qf[kd] = v;
        }
    }

    const half8 ONES = {(half_t)1, (half_t)1, (half_t)1, (half_t)1,
                        (half_t)1, (half_t)1, (half_t)1, (half_t)1};

    const half_t* Kg = qkv + (long)b * 1024 * 2304 + 768 + hh * 64;
    const half_t* Vg = Vt + (long)bh * 64 * 1024;

    const int srow_lo = (l >> 3);
    const int schunk = l & 7;

    auto STAGE = [&](int tile, int bf) {
#pragma unroll
        for (int c = 0; c < 2; ++c) {
            const int row = c * 32 + wv * 8 + srow_lo;
            const int sc_ = (schunk ^ (row & 7)) * 8;
            gload_lds16(Kg + (long)(tile * 64 + row) * 2304 + sc_,
                        &Kl[bf][(c * 32 + wv * 8) * 64]);
            gload_lds16(Vg + (long)row * 1024 + tile * 64 + sc_,
                        &Vl[bf][(c * 32 + wv * 8) * 64]);
        }
    };

    f32x16 o0 = {}, o1 = {}, lacc = {};

    STAGE(0, 0);

    for (int tt = 0; tt < 16; ++tt) {
        const int bf = tt & 1;
        if (tt < 15) {
            STAGE(tt + 1, bf ^ 1);
            asm volatile("s_waitcnt vmcnt(4)" ::: "memory");
        } else {
            asm volatile("s_waitcnt vmcnt(0)" ::: "memory");
        }
        __builtin_amdgcn_s_barrier();
        asm volatile("" ::: "memory");

        f32x16 s0 = {}, s1 = {};
        __builtin_amdgcn_s_setprio(1);
#pragma unroll
        for (int kd = 0; kd < 4; ++kd) {
            const int ch = ((kd * 2 + h2) ^ (q32 & 7)) * 8;
            half8 k0 = *(const half8*)&Kl[bf][q32 * 64 + ch];
            half8 k1 = *(const half8*)&Kl[bf][(32 + q32) * 64 + ch];
            s0 = __builtin_amdgcn_mfma_f32_32x32x16_f16(k0, qf[kd], s0, 0, 0, 0);
            s1 = __builtin_amdgcn_mfma_f32_32x32x16_f16(k1, qf[kd], s1, 0, 0, 0);
        }
        __builtin_amdgcn_s_setprio(0);

#pragma unroll
        for (int kc = 0; kc < 4; ++kc) {
            const f32x16& ss = (kc >> 1) ? s1 : s0;
            const int rb = (kc & 1) * 8;
            unsigned pw[4];
#pragma unroll
            for (int k2 = 0; k2 < 4; ++k2) {
                const float a = __builtin_amdgcn_exp2f(ss[rb + 2 * k2]);
                const float c = __builtin_amdgcn_exp2f(ss[rb + 2 * k2 + 1]);
                pw[k2] = __builtin_bit_cast(unsigned, __builtin_amdgcn_cvt_pkrtz(a, c));
            }
            uint4v uu = {pw[0], pw[1], pw[2], pw[3]};
            const half8 pf = __builtin_bit_cast(half8, uu);

            const int g0 = 2 * kc;
            const int a0 = q32 * 64 + ((g0 ^ (q32 & 7)) * 8) + 4 * h2;
            const int a1 = q32 * 64 + (((g0 + 1) ^ (q32 & 7)) * 8) + 4 * h2;
            const int r2 = 32 + q32;
            const int b0 = r2 * 64 + ((g0 ^ (r2 & 7)) * 8) + 4 * h2;
            const int b1 = r2 * 64 + (((g0 + 1) ^ (r2 & 7)) * 8) + 4 * h2;
            half4_t va0 = *(const half4_t*)&Vl[bf][a0];
            half4_t va1 = *(const half4_t*)&Vl[bf][a1];
            half4_t vb0 = *(const half4_t*)&Vl[bf][b0];
            half4_t vb1 = *(const half4_t*)&Vl[bf][b1];
            half8 vf0 = {va0[0], va0[1], va0[2], va0[3], va1[0], va1[1], va1[2], va1[3]};
            half8 vf1 = {vb0[0], vb0[1], vb0[2], vb0[3], vb1[0], vb1[1], vb1[2], vb1[3]};

            __builtin_amdgcn_s_setprio(1);
            o0 = __builtin_amdgcn_mfma_f32_32x32x16_f16(vf0, pf, o0, 0, 0, 0);
            o1 = __builtin_amdgcn_mfma_f32_32x32x16_f16(vf1, pf, o1, 0, 0, 0);
            lacc = __builtin_amdgcn_mfma_f32_32x32x16_f16(ONES, pf, lacc, 0, 0, 0);
            __builtin_amdgcn_s_setprio(0);
        }

        asm volatile("" ::: "memory");
        __builtin_amdgcn_s_barrier();
    }

    const float hmv = head_mask[b * 12 + hh];
    const float sc = hmv * hmv / lacc[0];
    half_t* Yp = Y + ((long)(b * 1024 + q0 + q32)) * 768 + hh * 64;
#pragma unroll
    for (int db = 0; db < 2; ++db) {
        const f32x16 oo = db ? o1 : o0;
#pragma unroll
        for (int rq = 0; rq < 4; ++rq) {
            half4_t pk;
#pragma unroll
            for (int i = 0; i < 4; ++i) pk[i] = (half_t)(oo[rq * 4 + i] * sc);
            *(half4_t*)(Yp + db * 32 + rq * 8 + h2 * 4) = pk;
        }
    }
}

// ---------------- launch ----------------
extern "C" void kernel_launch(void* const* d_in, const int* in_sizes, int n_in,
                              void* d_out, int out_size, void* d_ws, size_t ws_size,
                              hipStream_t stream) {
    const float* x   = (const float*)d_in[0];
    const float* hm  = (const float*)d_in[1];
    const float* q_w = (const float*)d_in[2];
    const float* q_b = (const float*)d_in[3];
    const float* k_w = (const float*)d_in[4];
    const float* k_b = (const float*)d_in[5];
    const float* v_w = (const float*)d_in[6];
    const float* v_b = (const float*)d_in[7];
    const float* p_w = (const float*)d_in[8];
    const float* p_b = (const float*)d_in[9];
    float* out = (float*)d_out;

    char* ws = (char*)d_ws;
    half_t* xh  = (half_t*)(ws);                    // 8192*768*2   = 12582912
    half_t* wc  = (half_t*)(ws + 12582912);         // [qkv|proj] weights fp16
    half_t* pwh = (half_t*)(ws + 16121856);         //   (proj part of wc)
    float*  bc  = (float*)(ws + 17301504);          // 2304*4
    half_t* qkv = (half_t*)(ws + 17310720);         // 8192*2304*2  = 37748736
    half_t* y   = (half_t*)(ws + 55059456);         // 8192*768*2   = 12582912
    half_t* Vt = (ws_size >= (size_t)67642368 + 12582912)
                     ? (half_t*)(ws + 67642368)
                     : (half_t*)d_out;

    cast_f32_f16<<<2048, 256, 0, stream>>>(x, xh, 8192 * 768);
    cast_w4<<<2304, 256, 0, stream>>>(q_w, k_w, v_w, p_w, wc);
    concat_bias<<<9, 256, 0, stream>>>(q_b, k_b, v_b, bc);

    gemm8p<half_t, true><<<dim3(32, 18), 512, 0, stream>>>(xh, wc, bc, qkv, Vt, 2304);
    attn5_kernel<<<dim3(96, 8), 256, 0, stream>>>(qkv, Vt, hm, y);
    gemm8p<float, false><<<dim3(32, 6), 512, 0, stream>>>(y, pwh, p_b, out, nullptr, 768);
}